// Round 9
// baseline (534.199 us; speedup 1.0000x reference)
//
#include <hip/hip_runtime.h>
#include <cstdint>
#include <cstddef>

#define B_  2
#define S_  2048
#define H_  768
#define NH  12
#define DH  64
#define RD  5
#define BN  (B_*NH)   // 24

typedef _Float16 f16;
typedef __attribute__((ext_vector_type(2))) _Float16 f16x2;
typedef __attribute__((ext_vector_type(8))) _Float16 f16x8;
typedef __attribute__((ext_vector_type(4))) float f32x4;

#define MFMA16(a, b, c) __builtin_amdgcn_mfma_f32_16x16x32_f16((a), (b), (c), 0, 0, 0)

#if __has_builtin(__builtin_amdgcn_exp2f)
__device__ __forceinline__ float exp2fast(float x) { return __builtin_amdgcn_exp2f(x); }
#else
__device__ __forceinline__ float exp2fast(float x) { return __expf(0.69314718056f * x); }
#endif

#define SCL 0.1803368801f   /* 0.125 * log2(e) */
#define L2E 1.44269504f

#define NX4 ((B_*S_*H_)/4)   // 786432
#define NW4 ((H_*H_)/4)      // 147456

__device__ __forceinline__ f16x2 pkrtz(float a, float b) {
    return __builtin_bit_cast(f16x2, __builtin_amdgcn_cvt_pkrtz(a, b));
}

// ---------------------------------------------------------------------------
// Kernel 0: fused fp32 -> fp16 conversion of x, Wq, Wk, Wv (one launch).
// ---------------------------------------------------------------------------
__global__ __launch_bounds__(256) void cvtall(
    const float* __restrict__ x,
    const float* __restrict__ wq, const float* __restrict__ wk,
    const float* __restrict__ wv,
    f16* __restrict__ xh, f16* __restrict__ wh)
{
    int idx = blockIdx.x * 256 + threadIdx.x;
    const int total4 = NX4 + 3 * NW4;
    if (idx >= total4) return;
    const float* src;
    f16* dst;
    int off;
    if (idx < NX4) {
        src = x; dst = xh; off = idx;
    } else {
        int r = idx - NX4;
        int which = r / NW4;
        off = r - which * NW4;
        src = (which == 0) ? wq : (which == 1) ? wk : wv;
        dst = wh + (size_t)which * H_ * H_;
    }
    float4 f = ((const float4*)src)[off];
    f16 h[4] = {(f16)f.x, (f16)f.y, (f16)f.z, (f16)f.w};
    ((ushort4*)dst)[off] = *(const ushort4*)h;
}

// ---------------------------------------------------------------------------
// Kernel 1: MFMA QKV projection (fp16 in/out).  One block: 64 rows x 64 cols
// of q,k,v (same x tile, three W tiles).  V written transposed vt[bn][d][s].
// grid (12, 64).
// ---------------------------------------------------------------------------
__global__ __launch_bounds__(256, 3) void qkv_gemm(
    const f16* __restrict__ xh, const f16* __restrict__ wh,
    const float* __restrict__ bq, const float* __restrict__ bk,
    const float* __restrict__ bv,
    f16* __restrict__ qo, f16* __restrict__ ko, f16* __restrict__ vt)
{
    __shared__ __align__(16) f16 Xs[64][72];
    __shared__ __align__(16) f16 Ws[3][64][72];

    const int tid = threadIdx.x;
    const int n  = blockIdx.x;          // head / 64-col tile
    const int m0 = blockIdx.y * 64;
    const int w = tid >> 6, lane = tid & 63;
    const int l15 = lane & 15, quad = lane >> 4;
    const int srow = tid >> 2, sc0 = (tid & 3) * 16;

    f32x4 acc[3][4];
#pragma unroll
    for (int i = 0; i < 3; ++i)
#pragma unroll
        for (int ns = 0; ns < 4; ++ns) acc[i][ns] = (f32x4){0.f, 0.f, 0.f, 0.f};

    const f16* xsrc = xh + (size_t)(m0 + srow) * H_ + sc0;
    const f16* wsrc = wh + (size_t)(n * 64 + srow) * H_ + sc0;

    for (int kc = 0; kc < 12; ++kc) {
        __syncthreads();
        {
            const f16* s0 = xsrc + kc * 64;
            *(f16x8*)&Xs[srow][sc0]     = *(const f16x8*)(s0);
            *(f16x8*)&Xs[srow][sc0 + 8] = *(const f16x8*)(s0 + 8);
        }
#pragma unroll
        for (int i = 0; i < 3; ++i) {
            const f16* s0 = wsrc + (size_t)i * H_ * H_ + kc * 64;
            *(f16x8*)&Ws[i][srow][sc0]     = *(const f16x8*)(s0);
            *(f16x8*)&Ws[i][srow][sc0 + 8] = *(const f16x8*)(s0 + 8);
        }
        __syncthreads();

        f16x8 a0 = *(const f16x8*)&Xs[w * 16 + l15][quad * 8];
        f16x8 a1 = *(const f16x8*)&Xs[w * 16 + l15][quad * 8 + 32];
#pragma unroll
        for (int i = 0; i < 3; ++i)
#pragma unroll
            for (int ns = 0; ns < 4; ++ns) {
                f16x8 b0 = *(const f16x8*)&Ws[i][ns * 16 + l15][quad * 8];
                f16x8 b1 = *(const f16x8*)&Ws[i][ns * 16 + l15][quad * 8 + 32];
                acc[i][ns] = MFMA16(a0, b0, acc[i][ns]);
                acc[i][ns] = MFMA16(a1, b1, acc[i][ns]);
            }
    }
    __syncthreads();

    const float* bias[3] = {bq, bk, bv};
    f16 (*T0)[72] = Xs;      // q
    f16 (*T1)[72] = Ws[0];   // k
    f16 (*T2)[72] = Ws[1];   // v
#pragma unroll
    for (int i = 0; i < 3; ++i) {
        f16 (*T)[72] = (i == 0) ? T0 : (i == 1) ? T1 : T2;
#pragma unroll
        for (int ns = 0; ns < 4; ++ns) {
            float bb = bias[i][n * 64 + ns * 16 + l15];
#pragma unroll
            for (int reg = 0; reg < 4; ++reg)
                T[w * 16 + quad * 4 + reg][ns * 16 + l15] =
                    (f16)(acc[i][ns][reg] + bb);
        }
    }
    __syncthreads();

    const int mrow = m0 + srow;
    const int bb2 = mrow >> 11, ss = mrow & 2047;
    {
        f16* dst = qo + ((size_t)(bb2 * NH + n) * S_ + ss) * DH + sc0;
        *(f16x8*)dst       = *(const f16x8*)&T0[srow][sc0];
        *(f16x8*)(dst + 8) = *(const f16x8*)&T0[srow][sc0 + 8];
    }
    {
        f16* dst = ko + ((size_t)(bb2 * NH + n) * S_ + ss) * DH + sc0;
        *(f16x8*)dst       = *(const f16x8*)&T1[srow][sc0];
        *(f16x8*)(dst + 8) = *(const f16x8*)&T1[srow][sc0 + 8];
    }
    {
        f16 tmp[16];
#pragma unroll
        for (int u = 0; u < 16; ++u) tmp[u] = T2[sc0 + u][srow];
        f16* dst = vt + ((size_t)(bb2 * NH + n) * DH + srow) * S_ + (m0 & 2047) + sc0;
        *(f16x8*)dst       = *(const f16x8*)&tmp[0];
        *(f16x8*)(dst + 8) = *(const f16x8*)&tmp[8];
    }
}

// ---------------------------------------------------------------------------
// Kernel 2: pack binary adjacency -> bytes, i-quad interleaved.
// ---------------------------------------------------------------------------
__global__ __launch_bounds__(256) void adjpack(
    const float* __restrict__ adj, unsigned char* __restrict__ adjp)
{
    const int idx = blockIdx.x * 256 + threadIdx.x;   // [0, 2^21)
    const int j  = idx & 2047;
    const int iq = (idx >> 11) & 511;
    const int b  = idx >> 20;
    unsigned int bits[4] = {0, 0, 0, 0};
#pragma unroll
    for (int r = 0; r < RD; ++r) {
#pragma unroll
        for (int ii = 0; ii < 4; ++ii) {
            float a = adj[(((size_t)(r * B_ + b) * S_) + iq * 4 + ii) * S_ + j];
            bits[ii] |= (a != 0.f ? 1u : 0u) << r;
        }
    }
    uchar4 pk;
    pk.x = (unsigned char)bits[0];
    pk.y = (unsigned char)bits[1];
    pk.z = (unsigned char)bits[2];
    pk.w = (unsigned char)bits[3];
    *(uchar4*)(adjp + (size_t)idx * 4) = pk;
}

// ---------------------------------------------------------------------------
// Kernel 3: MFMA flash attention.  768 blocks (XCD-swizzled), 4 waves, each
// wave owns 16 rows and the full j range; no barriers in the j-loop.
// Combine uses packed-f16 dot2: LUT maps 5-bit adjacency pattern to two
// packed {0,1} f16 mask pairs; relations 0-3 folded via v_dot2_f32_f16.
// Occupancy register-capped at 3 waves/SIMD; (256,3) spill-free, (256,4) not.
// ---------------------------------------------------------------------------
__global__ __launch_bounds__(256, 3) void attn(
    const f16* __restrict__ q, const f16* __restrict__ k, const f16* __restrict__ vt,
    const float* __restrict__ bili, const unsigned char* __restrict__ adjp,
    const float* __restrict__ mask, const float* __restrict__ absb,
    float* __restrict__ out)
{
    __shared__ __align__(16) char smem[9216 + 9216 + 128 + 256];
    f16*   Mt   = (f16*)smem;                    // [64][72] (prologue only)
    f16*   Pb   = (f16*)(smem + 9216);           // [4][16][72]
    float* lut  = (float*)(smem + 9216 + 9216);  // [32]  SCL * sum(bit*absb)
    uint2* lutm = (uint2*)(smem + 9216 + 9216 + 128);  // [32] packed f16 masks

    const int tid = threadIdx.x;
    const int idx = blockIdx.x;
    const int g = idx & 7;
    const int it = (idx >> 3) & 31;
    const int bn = 8 * (idx >> 8) + g;
    const int b = bn / NH, n = bn % NH;
    const int w = tid >> 6, lane = tid & 63;
    const int l15 = lane & 15, quad = lane >> 4;
    const int wi0 = it * 64 + w * 16;
    const size_t kbase = (size_t)bn * S_ * DH;

    if (tid < 32) {
        float a = 0.f;
#pragma unroll
        for (int r = 0; r < RD; ++r)
            if (tid & (1 << r)) a += absb[r * NH + n];
        lut[tid] = a * SCL;
        unsigned m01 = ((tid & 1) ? 0x00003C00u : 0u) | ((tid & 2) ? 0x3C000000u : 0u);
        unsigned m23 = ((tid & 4) ? 0x00003C00u : 0u) | ((tid & 8) ? 0x3C000000u : 0u);
        lutm[tid] = (uint2){m01, m23};
    }

    const f16* qrow = q + kbase + (size_t)(wi0 + l15) * DH + quad * 8;
    f16x8 aq0 = *(const f16x8*)(qrow);
    f16x8 aq1 = *(const f16x8*)(qrow + 32);

    f16* Pw = Pb + w * 16 * 72;

    // ---- build Q'_r A-frags via MFMA (M_r staged transposed in LDS) ----
    f16x8 aqp[RD][2];
#pragma unroll 1
    for (int r = 0; r < RD; ++r) {
        __syncthreads();
        {
            int p = tid >> 2, q0 = (tid & 3) * 16;
            const float* src = bili + ((size_t)(r * NH + n) * DH + p) * DH + q0;
            float4 g0 = ((const float4*)src)[0];
            float4 g1 = ((const float4*)src)[1];
            float4 g2 = ((const float4*)src)[2];
            float4 g3 = ((const float4*)src)[3];
            float mv[16] = {g0.x, g0.y, g0.z, g0.w, g1.x, g1.y, g1.z, g1.w,
                            g2.x, g2.y, g2.z, g2.w, g3.x, g3.y, g3.z, g3.w};
#pragma unroll
            for (int u = 0; u < 16; ++u) Mt[(q0 + u) * 72 + p] = (f16)mv[u];
        }
        __syncthreads();
#pragma unroll
        for (int ns = 0; ns < 4; ++ns) {
            f16x8 b0 = *(const f16x8*)&Mt[(ns * 16 + l15) * 72 + quad * 8];
            f16x8 b1 = *(const f16x8*)&Mt[(ns * 16 + l15) * 72 + quad * 8 + 32];
            f32x4 d = {0.f, 0.f, 0.f, 0.f};
            d = MFMA16(aq0, b0, d);
            d = MFMA16(aq1, b1, d);
#pragma unroll
            for (int reg = 0; reg < 4; ++reg)
                Pw[(quad * 4 + reg) * 72 + ns * 16 + l15] = (f16)d[reg];
        }
        aqp[r][0] = *(const f16x8*)&Pw[l15 * 72 + quad * 8];
        aqp[r][1] = *(const f16x8*)&Pw[l15 * 72 + quad * 8 + 32];
    }

    f16x8 ones;
#pragma unroll
    for (int u = 0; u < 8; ++u) ones[u] = (f16)1.0f;

    f32x4 o[4] = {{0,0,0,0},{0,0,0,0},{0,0,0,0},{0,0,0,0}};
    f32x4 lacc = {0.f, 0.f, 0.f, 0.f};
    float mrun[4] = {-1e30f, -1e30f, -1e30f, -1e30f};

    const unsigned char* adjrow =
        adjp + (size_t)(b * 512 + (wi0 >> 2) + quad) * (S_ * 4);
    const float* maskrow = mask + (size_t)b * S_;
    const f16* vtb = vt + (size_t)bn * DH * S_;

    for (int t = 0; t < 32; ++t) {
        const int j0 = t * 64;
        float sc[4][4];

#pragma unroll
        for (int js = 0; js < 4; ++js) {
            const int jcol = j0 + js * 16 + l15;
            const f16* kp = k + kbase + (size_t)jcol * DH + quad * 8;
            f16x8 bk0 = *(const f16x8*)(kp);
            f16x8 bk1 = *(const f16x8*)(kp + 32);

            f32x4 aqk = {0.f, 0.f, 0.f, 0.f};
            aqk = MFMA16(aq0, bk0, aqk);
            aqk = MFMA16(aq1, bk1, aqk);
            f32x4 ar[RD];
#pragma unroll
            for (int r = 0; r < RD; ++r) {
                f32x4 z = {0.f, 0.f, 0.f, 0.f};
                z = MFMA16(aqp[r][0], bk0, z);
                z = MFMA16(aqp[r][1], bk1, z);
                ar[r] = z;
            }

            uchar4 a4 = *(const uchar4*)(adjrow + (size_t)jcol * 4);
            unsigned int bbits[4] = {a4.x, a4.y, a4.z, a4.w};
            float mkL = maskrow[jcol] * L2E;
#pragma unroll
            for (int reg = 0; reg < 4; ++reg) {
                unsigned int bt = bbits[reg];
                uint2 mm = lutm[bt];
                f16x2 m01 = __builtin_bit_cast(f16x2, mm.x);
                f16x2 m23 = __builtin_bit_cast(f16x2, mm.y);
                f16x2 p01 = pkrtz(ar[0][reg], ar[1][reg]);
                f16x2 p23 = pkrtz(ar[2][reg], ar[3][reg]);
                float s = aqk[reg];
                s = __builtin_amdgcn_fdot2(p01, m01, s, false);
                s = __builtin_amdgcn_fdot2(p23, m23, s, false);
                s = fmaf((float)((bt >> 4) & 1u), ar[4][reg], s);
                sc[js][reg] = fmaf(s, SCL, lut[bt] + mkL);
            }
        }

        // ---- online softmax (exp2 domain; rows in 16-lane groups) ----
        float alpha[4];
#pragma unroll
        for (int reg = 0; reg < 4; ++reg) {
            float nm = fmaxf(fmaxf(sc[0][reg], sc[1][reg]),
                             fmaxf(sc[2][reg], sc[3][reg]));
#pragma unroll
            for (int off = 1; off < 16; off <<= 1)
                nm = fmaxf(nm, __shfl_xor(nm, off));
            float mn = fmaxf(mrun[reg], nm);
            alpha[reg] = exp2fast(mrun[reg] - mn);
            mrun[reg] = mn;
        }
#pragma unroll
        for (int js = 0; js < 4; ++js)
#pragma unroll
            for (int reg = 0; reg < 4; ++reg) {
                float p = exp2fast(sc[js][reg] - mrun[reg]);
                Pw[(quad * 4 + reg) * 72 + js * 16 + l15] = (f16)p;
            }
#pragma unroll
        for (int reg = 0; reg < 4; ++reg) {
            lacc[reg] *= alpha[reg];
#pragma unroll
            for (int ds = 0; ds < 4; ++ds) o[ds][reg] *= alpha[reg];
        }

        // ---- PV + row-sum via MFMA ----
        f16x8 pa0 = *(const f16x8*)&Pw[l15 * 72 + quad * 8];
        f16x8 pa1 = *(const f16x8*)&Pw[l15 * 72 + quad * 8 + 32];
        lacc = MFMA16(pa0, ones, lacc);
        lacc = MFMA16(pa1, ones, lacc);
#pragma unroll
        for (int ds = 0; ds < 4; ++ds) {
            const f16* vp = vtb + (size_t)(ds * 16 + l15) * S_ + j0 + quad * 8;
            f16x8 bv0 = *(const f16x8*)(vp);
            f16x8 bv1 = *(const f16x8*)(vp + 32);
            o[ds] = MFMA16(pa0, bv0, o[ds]);
            o[ds] = MFMA16(pa1, bv1, o[ds]);
        }
    }

    // ---- epilogue ----
#pragma unroll
    for (int reg = 0; reg < 4; ++reg) {
        float inv = 1.f / lacc[reg];
        int i = wi0 + quad * 4 + reg;
#pragma unroll
        for (int ds = 0; ds < 4; ++ds)
            out[((size_t)b * S_ + i) * H_ + n * DH + ds * 16 + l15] =
                o[ds][reg] * inv;
    }
}

// ---------------------------------------------------------------------------
extern "C" void kernel_launch(void* const* d_in, const int* in_sizes, int n_in,
                              void* d_out, int out_size, void* d_ws, size_t ws_size,
                              hipStream_t stream)
{
    const float* hs   = (const float*)d_in[0];
    const float* mask = (const float*)d_in[1];
    const float* adj  = (const float*)d_in[2];
    const float* Wq   = (const float*)d_in[3];
    const float* bq   = (const float*)d_in[4];
    const float* Wk   = (const float*)d_in[5];
    const float* bk   = (const float*)d_in[6];
    const float* Wv   = (const float*)d_in[7];
    const float* bv   = (const float*)d_in[8];
    const float* bili = (const float*)d_in[9];
    const float* absb = (const float*)d_in[10];
    float* out = (float*)d_out;

    const size_t QKV = (size_t)BN * S_ * DH;       // 3.1M elems
    f16* q  = (f16*)d_ws;
    f16* k  = q + QKV;
    f16* vt = k + QKV;
    unsigned char* adjp = (unsigned char*)(vt + QKV);       // 8 MB
    f16* xh = (f16*)(adjp + (size_t)B_ * 512 * S_ * 4);
    f16* wh = xh + (size_t)B_ * S_ * H_;                    // Wq|Wk|Wv f16

    const int total4 = NX4 + 3 * NW4;
    cvtall<<<(total4 + 255) / 256, 256, 0, stream>>>(hs, Wq, Wk, Wv, xh, wh);
    qkv_gemm<<<dim3(12, 64), 256, 0, stream>>>(xh, wh, bq, bk, bv, q, k, vt);
    adjpack<<<8192, 256, 0, stream>>>(adj, adjp);
    attn<<<768, 256, 0, stream>>>(q, k, vt, bili, adjp, mask, absb, out);
}

// Round 10
// 532.423 us; speedup vs baseline: 1.0033x; 1.0033x over previous
//
#include <hip/hip_runtime.h>
#include <cstdint>
#include <cstddef>

#define B_  2
#define S_  2048
#define H_  768
#define NH  12
#define DH  64
#define RD  5
#define BN  (B_*NH)   // 24

typedef _Float16 f16;
typedef __attribute__((ext_vector_type(8))) _Float16 f16x8;
typedef __attribute__((ext_vector_type(4))) float f32x4;

#define MFMA16(a, b, c) __builtin_amdgcn_mfma_f32_16x16x32_f16((a), (b), (c), 0, 0, 0)

#if __has_builtin(__builtin_amdgcn_exp2f)
__device__ __forceinline__ float exp2fast(float x) { return __builtin_amdgcn_exp2f(x); }
#else
__device__ __forceinline__ float exp2fast(float x) { return __expf(0.69314718056f * x); }
#endif

#define SCL 0.1803368801f   /* 0.125 * log2(e) */
#define L2E 1.44269504f

#define NX4 ((B_*S_*H_)/4)   // 786432
#define NW4 ((H_*H_)/4)      // 147456

typedef __attribute__((address_space(3))) void       lds_vp;
typedef __attribute__((address_space(1))) const void glb_vp;
#define GLDS16(src, dst) \
    __builtin_amdgcn_global_load_lds((glb_vp*)(src), (lds_vp*)(dst), 16, 0, 0)

// ---------------------------------------------------------------------------
// Kernel 0: fused fp32 -> fp16 conversion of x, Wq, Wk, Wv (one launch).
// ---------------------------------------------------------------------------
__global__ __launch_bounds__(256) void cvtall(
    const float* __restrict__ x,
    const float* __restrict__ wq, const float* __restrict__ wk,
    const float* __restrict__ wv,
    f16* __restrict__ xh, f16* __restrict__ wh)
{
    int idx = blockIdx.x * 256 + threadIdx.x;
    const int total4 = NX4 + 3 * NW4;
    if (idx >= total4) return;
    const float* src;
    f16* dst;
    int off;
    if (idx < NX4) {
        src = x; dst = xh; off = idx;
    } else {
        int r = idx - NX4;
        int which = r / NW4;
        off = r - which * NW4;
        src = (which == 0) ? wq : (which == 1) ? wk : wv;
        dst = wh + (size_t)which * H_ * H_;
    }
    float4 f = ((const float4*)src)[off];
    f16 h[4] = {(f16)f.x, (f16)f.y, (f16)f.z, (f16)f.w};
    ((ushort4*)dst)[off] = *(const ushort4*)h;
}

// ---------------------------------------------------------------------------
// Kernel 1: MFMA QKV projection (fp16 in/out).  One block: 64 rows x 64 cols
// of q,k,v (same x tile, three W tiles).  V written transposed vt[bn][d][s].
// grid (12, 64).
// ---------------------------------------------------------------------------
__global__ __launch_bounds__(256, 3) void qkv_gemm(
    const f16* __restrict__ xh, const f16* __restrict__ wh,
    const float* __restrict__ bq, const float* __restrict__ bk,
    const float* __restrict__ bv,
    f16* __restrict__ qo, f16* __restrict__ ko, f16* __restrict__ vt)
{
    __shared__ __align__(16) f16 Xs[64][72];
    __shared__ __align__(16) f16 Ws[3][64][72];

    const int tid = threadIdx.x;
    const int n  = blockIdx.x;          // head / 64-col tile
    const int m0 = blockIdx.y * 64;
    const int w = tid >> 6, lane = tid & 63;
    const int l15 = lane & 15, quad = lane >> 4;
    const int srow = tid >> 2, sc0 = (tid & 3) * 16;

    f32x4 acc[3][4];
#pragma unroll
    for (int i = 0; i < 3; ++i)
#pragma unroll
        for (int ns = 0; ns < 4; ++ns) acc[i][ns] = (f32x4){0.f, 0.f, 0.f, 0.f};

    const f16* xsrc = xh + (size_t)(m0 + srow) * H_ + sc0;
    const f16* wsrc = wh + (size_t)(n * 64 + srow) * H_ + sc0;

    for (int kc = 0; kc < 12; ++kc) {
        __syncthreads();
        {
            const f16* s0 = xsrc + kc * 64;
            *(f16x8*)&Xs[srow][sc0]     = *(const f16x8*)(s0);
            *(f16x8*)&Xs[srow][sc0 + 8] = *(const f16x8*)(s0 + 8);
        }
#pragma unroll
        for (int i = 0; i < 3; ++i) {
            const f16* s0 = wsrc + (size_t)i * H_ * H_ + kc * 64;
            *(f16x8*)&Ws[i][srow][sc0]     = *(const f16x8*)(s0);
            *(f16x8*)&Ws[i][srow][sc0 + 8] = *(const f16x8*)(s0 + 8);
        }
        __syncthreads();

        f16x8 a0 = *(const f16x8*)&Xs[w * 16 + l15][quad * 8];
        f16x8 a1 = *(const f16x8*)&Xs[w * 16 + l15][quad * 8 + 32];
#pragma unroll
        for (int i = 0; i < 3; ++i)
#pragma unroll
            for (int ns = 0; ns < 4; ++ns) {
                f16x8 b0 = *(const f16x8*)&Ws[i][ns * 16 + l15][quad * 8];
                f16x8 b1 = *(const f16x8*)&Ws[i][ns * 16 + l15][quad * 8 + 32];
                acc[i][ns] = MFMA16(a0, b0, acc[i][ns]);
                acc[i][ns] = MFMA16(a1, b1, acc[i][ns]);
            }
    }
    __syncthreads();

    const float* bias[3] = {bq, bk, bv};
    f16 (*T0)[72] = Xs;      // q
    f16 (*T1)[72] = Ws[0];   // k
    f16 (*T2)[72] = Ws[1];   // v
#pragma unroll
    for (int i = 0; i < 3; ++i) {
        f16 (*T)[72] = (i == 0) ? T0 : (i == 1) ? T1 : T2;
#pragma unroll
        for (int ns = 0; ns < 4; ++ns) {
            float bb = bias[i][n * 64 + ns * 16 + l15];
#pragma unroll
            for (int reg = 0; reg < 4; ++reg)
                T[w * 16 + quad * 4 + reg][ns * 16 + l15] =
                    (f16)(acc[i][ns][reg] + bb);
        }
    }
    __syncthreads();

    const int mrow = m0 + srow;
    const int bb2 = mrow >> 11, ss = mrow & 2047;
    {
        f16* dst = qo + ((size_t)(bb2 * NH + n) * S_ + ss) * DH + sc0;
        *(f16x8*)dst       = *(const f16x8*)&T0[srow][sc0];
        *(f16x8*)(dst + 8) = *(const f16x8*)&T0[srow][sc0 + 8];
    }
    {
        f16* dst = ko + ((size_t)(bb2 * NH + n) * S_ + ss) * DH + sc0;
        *(f16x8*)dst       = *(const f16x8*)&T1[srow][sc0];
        *(f16x8*)(dst + 8) = *(const f16x8*)&T1[srow][sc0 + 8];
    }
    {
        f16 tmp[16];
#pragma unroll
        for (int u = 0; u < 16; ++u) tmp[u] = T2[sc0 + u][srow];
        f16* dst = vt + ((size_t)(bb2 * NH + n) * DH + srow) * S_ + (m0 & 2047) + sc0;
        *(f16x8*)dst       = *(const f16x8*)&tmp[0];
        *(f16x8*)(dst + 8) = *(const f16x8*)&tmp[8];
    }
}

// ---------------------------------------------------------------------------
// Kernel 2: pack binary adjacency -> bytes, i-quad interleaved.
// ---------------------------------------------------------------------------
__global__ __launch_bounds__(256) void adjpack(
    const float* __restrict__ adj, unsigned char* __restrict__ adjp)
{
    const int idx = blockIdx.x * 256 + threadIdx.x;   // [0, 2^21)
    const int j  = idx & 2047;
    const int iq = (idx >> 11) & 511;
    const int b  = idx >> 20;
    unsigned int bits[4] = {0, 0, 0, 0};
#pragma unroll
    for (int r = 0; r < RD; ++r) {
#pragma unroll
        for (int ii = 0; ii < 4; ++ii) {
            float a = adj[(((size_t)(r * B_ + b) * S_) + iq * 4 + ii) * S_ + j];
            bits[ii] |= (a != 0.f ? 1u : 0u) << r;
        }
    }
    uchar4 pk;
    pk.x = (unsigned char)bits[0];
    pk.y = (unsigned char)bits[1];
    pk.z = (unsigned char)bits[2];
    pk.w = (unsigned char)bits[3];
    *(uchar4*)(adjp + (size_t)idx * 4) = pk;
}

// ---------------------------------------------------------------------------
// Kernel 3: MFMA flash attention with K/V double-buffered LDS staging via
// global_load_lds (async DMA).  One barrier per j-iter; stage(t+1) issued
// AFTER the barrier so its vmcnt drain happens one full compute phase later.
// XOR chunk-swizzle (source-side scatter) makes all ds_read_b128 bank-optimal.
// 768 blocks (XCD-swizzled), 4 waves; per-wave rows, full j-range.
// ---------------------------------------------------------------------------
__global__ __launch_bounds__(256, 3) void attn(
    const f16* __restrict__ q, const f16* __restrict__ k, const f16* __restrict__ vt,
    const float* __restrict__ bili, const unsigned char* __restrict__ adjp,
    const float* __restrict__ mask, const float* __restrict__ absb,
    float* __restrict__ out)
{
    __shared__ __align__(16) f16 Kb[2][4096];   // [buf][row j (64) x 64 d], swizzled
    __shared__ __align__(16) f16 Vb[2][4096];   // [buf][row d (64) x 64 j], swizzled
    __shared__ __align__(16) f16 Pb[4][1024];   // per-wave P / Q' round-trip, swizzled

    const int tid = threadIdx.x;
    const int idx = blockIdx.x;
    const int g = idx & 7;
    const int it = (idx >> 3) & 31;
    const int bn = 8 * (idx >> 8) + g;
    const int b = bn / NH, n = bn % NH;
    const int w = tid >> 6, lane = tid & 63;
    const int l15 = lane & 15, quad = lane >> 4;
    const int wi0 = it * 64 + w * 16;
    const size_t kbase = (size_t)bn * S_ * DH;

    const f16* qrow = q + kbase + (size_t)(wi0 + l15) * DH + quad * 8;
    f16x8 aq0 = *(const f16x8*)(qrow);
    f16x8 aq1 = *(const f16x8*)(qrow + 32);

    f16* Pw = &Pb[w][0];
    f16* Mt = &Kb[0][0];                 // prologue alias (4608 of 8192 f16)
    const int pswz0 = ((quad ^ (l15 & 7)) << 3);        // chunk quad,   swizzled
    const int pswz1 = (((quad + 4) ^ (l15 & 7)) << 3);  // chunk quad+4, swizzled

    // ---- build Q'_r A-frags via MFMA (M_r staged transposed in Mt) ----
    f16x8 aqp[RD][2];
#pragma unroll 1
    for (int r = 0; r < RD; ++r) {
        __syncthreads();
        {
            int p = tid >> 2, q0 = (tid & 3) * 16;
            const float* src = bili + ((size_t)(r * NH + n) * DH + p) * DH + q0;
            float4 g0 = ((const float4*)src)[0];
            float4 g1 = ((const float4*)src)[1];
            float4 g2 = ((const float4*)src)[2];
            float4 g3 = ((const float4*)src)[3];
            float mv[16] = {g0.x, g0.y, g0.z, g0.w, g1.x, g1.y, g1.z, g1.w,
                            g2.x, g2.y, g2.z, g2.w, g3.x, g3.y, g3.z, g3.w};
#pragma unroll
            for (int u = 0; u < 16; ++u) Mt[(q0 + u) * 72 + p] = (f16)mv[u];
        }
        __syncthreads();
#pragma unroll
        for (int ns = 0; ns < 4; ++ns) {
            f16x8 b0 = *(const f16x8*)&Mt[(ns * 16 + l15) * 72 + quad * 8];
            f16x8 b1 = *(const f16x8*)&Mt[(ns * 16 + l15) * 72 + quad * 8 + 32];
            f32x4 d = {0.f, 0.f, 0.f, 0.f};
            d = MFMA16(aq0, b0, d);
            d = MFMA16(aq1, b1, d);
            const int cb = ns * 2 + (l15 >> 3);
#pragma unroll
            for (int reg = 0; reg < 4; ++reg) {
                const int row = quad * 4 + reg;
                Pw[row * 64 + ((cb ^ (row & 7)) << 3) + (l15 & 7)] = (f16)d[reg];
            }
        }
        aqp[r][0] = *(const f16x8*)&Pw[l15 * 64 + pswz0];
        aqp[r][1] = *(const f16x8*)&Pw[l15 * 64 + pswz1];
    }
    __syncthreads();   // Mt dead; Kb[0] free for DMA staging

    // ---- staging setup ----
    const f16* kg  = k + kbase;
    const f16* vtb = vt + (size_t)bn * DH * S_;
    const int rsub = lane >> 3;                      // row within 8-row group
    const int csw8 = (((lane & 7) ^ (rsub & 7)) << 3);  // swizzled source chunk

    auto stage = [&](int buf, int jt0) {
#pragma unroll
        for (int ii = 0; ii < 2; ++ii) {
            const int inst = w * 2 + ii;             // 8 instrs over 4 waves
            const int row = inst * 8 + rsub;
            GLDS16(kg + (size_t)(jt0 + row) * DH + csw8, &Kb[buf][inst * 512]);
            GLDS16(vtb + (size_t)row * S_ + jt0 + csw8, &Vb[buf][inst * 512]);
        }
    };

    stage(0, 0);

    float ab[RD];
#pragma unroll
    for (int r = 0; r < RD; ++r) ab[r] = absb[r * NH + n];

    f16x8 ones;
#pragma unroll
    for (int u = 0; u < 8; ++u) ones[u] = (f16)1.0f;

    f32x4 o[4] = {{0,0,0,0},{0,0,0,0},{0,0,0,0},{0,0,0,0}};
    f32x4 lacc = {0.f, 0.f, 0.f, 0.f};
    float mrun[4] = {-1e30f, -1e30f, -1e30f, -1e30f};

    const unsigned char* adjrow =
        adjp + (size_t)(b * 512 + (wi0 >> 2) + quad) * (S_ * 4);
    const float* maskrow = mask + (size_t)b * S_;

    for (int t = 0; t < 32; ++t) {
        __syncthreads();                    // drains stage(t) (issued 1 iter ago)
        if (t < 31) stage((t + 1) & 1, (t + 1) * 64);
        const f16* KT = &Kb[t & 1][0];
        const f16* VT = &Vb[t & 1][0];
        const int j0 = t * 64;
        float sc[4][4];

#pragma unroll
        for (int js = 0; js < 4; ++js) {
            const int jrow = js * 16 + l15;
            f16x8 bk0 = *(const f16x8*)&KT[jrow * 64 + pswz0];
            f16x8 bk1 = *(const f16x8*)&KT[jrow * 64 + pswz1];

            f32x4 aqk = {0.f, 0.f, 0.f, 0.f};
            aqk = MFMA16(aq0, bk0, aqk);
            aqk = MFMA16(aq1, bk1, aqk);
            f32x4 ar[RD];
#pragma unroll
            for (int r = 0; r < RD; ++r) {
                f32x4 z = {0.f, 0.f, 0.f, 0.f};
                z = MFMA16(aqp[r][0], bk0, z);
                z = MFMA16(aqp[r][1], bk1, z);
                ar[r] = z;
            }

            const int jcol = j0 + jrow;
            uchar4 a4 = *(const uchar4*)(adjrow + (size_t)jcol * 4);
            unsigned int bbits[4] = {a4.x, a4.y, a4.z, a4.w};
            float mkL = maskrow[jcol] * L2E;
#pragma unroll
            for (int reg = 0; reg < 4; ++reg) {
                float s = aqk[reg];
                unsigned int bt = bbits[reg];
#pragma unroll
                for (int r = 0; r < RD; ++r)
                    s = fmaf((float)((bt >> r) & 1u), ar[r][reg] + ab[r], s);
                sc[js][reg] = fmaf(s, SCL, mkL);
            }
        }

        // ---- online softmax (exp2 domain; rows in 16-lane groups) ----
        float alpha[4];
#pragma unroll
        for (int reg = 0; reg < 4; ++reg) {
            float nm = fmaxf(fmaxf(sc[0][reg], sc[1][reg]),
                             fmaxf(sc[2][reg], sc[3][reg]));
#pragma unroll
            for (int off = 1; off < 16; off <<= 1)
                nm = fmaxf(nm, __shfl_xor(nm, off));
            float mn = fmaxf(mrun[reg], nm);
            alpha[reg] = exp2fast(mrun[reg] - mn);
            mrun[reg] = mn;
        }
#pragma unroll
        for (int js = 0; js < 4; ++js) {
            const int cb = js * 2 + (l15 >> 3);
#pragma unroll
            for (int reg = 0; reg < 4; ++reg) {
                const int row = quad * 4 + reg;
                float p = exp2fast(sc[js][reg] - mrun[reg]);
                Pw[row * 64 + ((cb ^ (row & 7)) << 3) + (l15 & 7)] = (f16)p;
            }
        }
#pragma unroll
        for (int reg = 0; reg < 4; ++reg) {
            lacc[reg] *= alpha[reg];
#pragma unroll
            for (int ds = 0; ds < 4; ++ds) o[ds][reg] *= alpha[reg];
        }

        // ---- PV + row-sum via MFMA (V from swizzled LDS) ----
        f16x8 pa0 = *(const f16x8*)&Pw[l15 * 64 + pswz0];
        f16x8 pa1 = *(const f16x8*)&Pw[l15 * 64 + pswz1];
        lacc = MFMA16(pa0, ones, lacc);
        lacc = MFMA16(pa1, ones, lacc);
#pragma unroll
        for (int ds = 0; ds < 4; ++ds) {
            const int vrow = ds * 16 + l15;
            f16x8 bv0 = *(const f16x8*)&VT[vrow * 64 + pswz0];
            f16x8 bv1 = *(const f16x8*)&VT[vrow * 64 + pswz1];
            o[ds] = MFMA16(pa0, bv0, o[ds]);
            o[ds] = MFMA16(pa1, bv1, o[ds]);
        }
    }

    // ---- epilogue ----
#pragma unroll
    for (int reg = 0; reg < 4; ++reg) {
        float inv = 1.f / lacc[reg];
        int i = wi0 + quad * 4 + reg;
#pragma unroll
        for (int ds = 0; ds < 4; ++ds)
            out[((size_t)b * S_ + i) * H_ + n * DH + ds * 16 + l15] =
                o[ds][reg] * inv;
    }
}

// ---------------------------------------------------------------------------
extern "C" void kernel_launch(void* const* d_in, const int* in_sizes, int n_in,
                              void* d_out, int out_size, void* d_ws, size_t ws_size,
                              hipStream_t stream)
{
    const float* hs   = (const float*)d_in[0];
    const float* mask = (const float*)d_in[1];
    const float* adj  = (const float*)d_in[2];
    const float* Wq   = (const float*)d_in[3];
    const float* bq   = (const float*)d_in[4];
    const float* Wk   = (const float*)d_in[5];
    const float* bk   = (const float*)d_in[6];
    const float* Wv   = (const float*)d_in[7];
    const float* bv   = (const float*)d_in[8];
    const float* bili = (const float*)d_in[9];
    const float* absb = (const float*)d_in[10];
    float* out = (float*)d_out;

    const size_t QKV = (size_t)BN * S_ * DH;       // 3.1M elems
    f16* q  = (f16*)d_ws;
    f16* k  = q + QKV;
    f16* vt = k + QKV;
    unsigned char* adjp = (unsigned char*)(vt + QKV);       // 8 MB
    f16* xh = (f16*)(adjp + (size_t)B_ * 512 * S_ * 4);
    f16* wh = xh + (size_t)B_ * S_ * H_;                    // Wq|Wk|Wv f16

    const int total4 = NX4 + 3 * NW4;
    cvtall<<<(total4 + 255) / 256, 256, 0, stream>>>(hs, Wq, Wk, Wv, xh, wh);
    qkv_gemm<<<dim3(12, 64), 256, 0, stream>>>(xh, wh, bq, bk, bv, q, k, vt);
    adjpack<<<8192, 256, 0, stream>>>(adj, adjp);
    attn<<<768, 256, 0, stream>>>(q, k, vt, bili, adjp, mask, absb, out);
}

// Round 11
// 519.099 us; speedup vs baseline: 1.0291x; 1.0257x over previous
//
#include <hip/hip_runtime.h>
#include <cstdint>
#include <cstddef>

#define B_  2
#define S_  2048
#define H_  768
#define NH  12
#define DH  64
#define RD  5
#define BN  (B_*NH)   // 24

typedef _Float16 f16;
typedef __attribute__((ext_vector_type(8))) _Float16 f16x8;
typedef __attribute__((ext_vector_type(4))) float f32x4;

#define MFMA16(a, b, c) __builtin_amdgcn_mfma_f32_16x16x32_f16((a), (b), (c), 0, 0, 0)

#if __has_builtin(__builtin_amdgcn_exp2f)
__device__ __forceinline__ float exp2fast(float x) { return __builtin_amdgcn_exp2f(x); }
#else
__device__ __forceinline__ float exp2fast(float x) { return __expf(0.69314718056f * x); }
#endif

#define SCL 0.1803368801f   /* 0.125 * log2(e) */
#define L2E 1.44269504f

#define NX4 ((B_*S_*H_)/4)   // 786432
#define NW4 ((H_*H_)/4)      // 147456

// ---------------------------------------------------------------------------
// Kernel 0: fused fp32 -> fp16 conversion of x, Wq, Wk, Wv (one launch).
// ---------------------------------------------------------------------------
__global__ __launch_bounds__(256) void cvtall(
    const float* __restrict__ x,
    const float* __restrict__ wq, const float* __restrict__ wk,
    const float* __restrict__ wv,
    f16* __restrict__ xh, f16* __restrict__ wh)
{
    int idx = blockIdx.x * 256 + threadIdx.x;
    const int total4 = NX4 + 3 * NW4;
    if (idx >= total4) return;
    const float* src;
    f16* dst;
    int off;
    if (idx < NX4) {
        src = x; dst = xh; off = idx;
    } else {
        int r = idx - NX4;
        int which = r / NW4;
        off = r - which * NW4;
        src = (which == 0) ? wq : (which == 1) ? wk : wv;
        dst = wh + (size_t)which * H_ * H_;
    }
    float4 f = ((const float4*)src)[off];
    f16 h[4] = {(f16)f.x, (f16)f.y, (f16)f.z, (f16)f.w};
    ((ushort4*)dst)[off] = *(const ushort4*)h;
}

// ---------------------------------------------------------------------------
// Kernel 1: MFMA QKV projection (fp16 in/out).  One block: 64 rows x 64 cols
// of q,k,v (same x tile, three W tiles).  V written transposed vt[bn][d][s].
// grid (12, 64).
// ---------------------------------------------------------------------------
__global__ __launch_bounds__(256, 3) void qkv_gemm(
    const f16* __restrict__ xh, const f16* __restrict__ wh,
    const float* __restrict__ bq, const float* __restrict__ bk,
    const float* __restrict__ bv,
    f16* __restrict__ qo, f16* __restrict__ ko, f16* __restrict__ vt)
{
    __shared__ __align__(16) f16 Xs[64][72];
    __shared__ __align__(16) f16 Ws[3][64][72];

    const int tid = threadIdx.x;
    const int n  = blockIdx.x;          // head / 64-col tile
    const int m0 = blockIdx.y * 64;
    const int w = tid >> 6, lane = tid & 63;
    const int l15 = lane & 15, quad = lane >> 4;
    const int srow = tid >> 2, sc0 = (tid & 3) * 16;

    f32x4 acc[3][4];
#pragma unroll
    for (int i = 0; i < 3; ++i)
#pragma unroll
        for (int ns = 0; ns < 4; ++ns) acc[i][ns] = (f32x4){0.f, 0.f, 0.f, 0.f};

    const f16* xsrc = xh + (size_t)(m0 + srow) * H_ + sc0;
    const f16* wsrc = wh + (size_t)(n * 64 + srow) * H_ + sc0;

    for (int kc = 0; kc < 12; ++kc) {
        __syncthreads();
        {
            const f16* s0 = xsrc + kc * 64;
            *(f16x8*)&Xs[srow][sc0]     = *(const f16x8*)(s0);
            *(f16x8*)&Xs[srow][sc0 + 8] = *(const f16x8*)(s0 + 8);
        }
#pragma unroll
        for (int i = 0; i < 3; ++i) {
            const f16* s0 = wsrc + (size_t)i * H_ * H_ + kc * 64;
            *(f16x8*)&Ws[i][srow][sc0]     = *(const f16x8*)(s0);
            *(f16x8*)&Ws[i][srow][sc0 + 8] = *(const f16x8*)(s0 + 8);
        }
        __syncthreads();

        f16x8 a0 = *(const f16x8*)&Xs[w * 16 + l15][quad * 8];
        f16x8 a1 = *(const f16x8*)&Xs[w * 16 + l15][quad * 8 + 32];
#pragma unroll
        for (int i = 0; i < 3; ++i)
#pragma unroll
            for (int ns = 0; ns < 4; ++ns) {
                f16x8 b0 = *(const f16x8*)&Ws[i][ns * 16 + l15][quad * 8];
                f16x8 b1 = *(const f16x8*)&Ws[i][ns * 16 + l15][quad * 8 + 32];
                acc[i][ns] = MFMA16(a0, b0, acc[i][ns]);
                acc[i][ns] = MFMA16(a1, b1, acc[i][ns]);
            }
    }
    __syncthreads();

    const float* bias[3] = {bq, bk, bv};
    f16 (*T0)[72] = Xs;      // q
    f16 (*T1)[72] = Ws[0];   // k
    f16 (*T2)[72] = Ws[1];   // v
#pragma unroll
    for (int i = 0; i < 3; ++i) {
        f16 (*T)[72] = (i == 0) ? T0 : (i == 1) ? T1 : T2;
#pragma unroll
        for (int ns = 0; ns < 4; ++ns) {
            float bb = bias[i][n * 64 + ns * 16 + l15];
#pragma unroll
            for (int reg = 0; reg < 4; ++reg)
                T[w * 16 + quad * 4 + reg][ns * 16 + l15] =
                    (f16)(acc[i][ns][reg] + bb);
        }
    }
    __syncthreads();

    const int mrow = m0 + srow;
    const int bb2 = mrow >> 11, ss = mrow & 2047;
    {
        f16* dst = qo + ((size_t)(bb2 * NH + n) * S_ + ss) * DH + sc0;
        *(f16x8*)dst       = *(const f16x8*)&T0[srow][sc0];
        *(f16x8*)(dst + 8) = *(const f16x8*)&T0[srow][sc0 + 8];
    }
    {
        f16* dst = ko + ((size_t)(bb2 * NH + n) * S_ + ss) * DH + sc0;
        *(f16x8*)dst       = *(const f16x8*)&T1[srow][sc0];
        *(f16x8*)(dst + 8) = *(const f16x8*)&T1[srow][sc0 + 8];
    }
    {
        f16 tmp[16];
#pragma unroll
        for (int u = 0; u < 16; ++u) tmp[u] = T2[sc0 + u][srow];
        f16* dst = vt + ((size_t)(bb2 * NH + n) * DH + srow) * S_ + (m0 & 2047) + sc0;
        *(f16x8*)dst       = *(const f16x8*)&tmp[0];
        *(f16x8*)(dst + 8) = *(const f16x8*)&tmp[8];
    }
}

// ---------------------------------------------------------------------------
// Kernel 2: pack binary adjacency -> bytes, i-quad interleaved, VECTORIZED.
// Each thread handles 4 consecutive j's: 20 float4 loads (1KB/wave/stream)
// + one contiguous uint4 (16B) store.  grid 2048 x 256.
// (Old scalar version ran ~270 us -- 650 GB/s on a 168 MB compulsory read.)
// ---------------------------------------------------------------------------
__global__ __launch_bounds__(256) void adjpack(
    const float* __restrict__ adj, unsigned char* __restrict__ adjp)
{
    const int idx4 = blockIdx.x * 256 + threadIdx.x;   // [0, 2^19)
    const int j4 = idx4 & 511;          // j = j4*4
    const int iq = (idx4 >> 9) & 511;
    const int b  = idx4 >> 18;
    unsigned int wbits[4] = {0, 0, 0, 0};   // per-j packed (ii in byte lanes)
#pragma unroll
    for (int r = 0; r < RD; ++r) {
#pragma unroll
        for (int ii = 0; ii < 4; ++ii) {
            float4 v = *(const float4*)(adj +
                (((size_t)(r * B_ + b) * S_) + iq * 4 + ii) * S_ + j4 * 4);
            float vv[4] = {v.x, v.y, v.z, v.w};
#pragma unroll
            for (int jj = 0; jj < 4; ++jj)
                wbits[jj] |= (vv[jj] != 0.f ? 1u : 0u) << (r + 8 * ii);
        }
    }
    uint4 pk = {wbits[0], wbits[1], wbits[2], wbits[3]};
    *(uint4*)(adjp + ((size_t)(b * 512 + iq) * S_ + j4 * 4) * 4) = pk;
}

// ---------------------------------------------------------------------------
// Kernel 3: MFMA flash attention (measured-best R7 structure, 230 us).
// 768 blocks (XCD-swizzled), 4 waves, each wave owns 16 rows and the full
// j range; no barriers in the j-loop.  Direct per-lane K/V global loads
// (L1/L2 shared across the 32 blocks per bn -- DMA staging regressed this).
// Occupancy register-capped at 3 waves/SIMD; (256,3) spill-free, (256,4) not.
// ---------------------------------------------------------------------------
__global__ __launch_bounds__(256, 3) void attn(
    const f16* __restrict__ q, const f16* __restrict__ k, const f16* __restrict__ vt,
    const float* __restrict__ bili, const unsigned char* __restrict__ adjp,
    const float* __restrict__ mask, const float* __restrict__ absb,
    float* __restrict__ out)
{
    __shared__ __align__(16) char smem[9216 + 9216 + 128];
    f16*   Mt  = (f16*)smem;                    // [64][72] (prologue only)
    f16*   Pb  = (f16*)(smem + 9216);           // [4][16][72]
    float* lut = (float*)(smem + 9216 + 9216);  // [32]

    const int tid = threadIdx.x;
    const int idx = blockIdx.x;
    const int g = idx & 7;
    const int it = (idx >> 3) & 31;
    const int bn = 8 * (idx >> 8) + g;
    const int b = bn / NH, n = bn % NH;
    const int w = tid >> 6, lane = tid & 63;
    const int l15 = lane & 15, quad = lane >> 4;
    const int wi0 = it * 64 + w * 16;
    const size_t kbase = (size_t)bn * S_ * DH;

    if (tid < 32) {
        float a = 0.f;
#pragma unroll
        for (int r = 0; r < RD; ++r)
            if (tid & (1 << r)) a += absb[r * NH + n];
        lut[tid] = a * SCL;
    }

    const f16* qrow = q + kbase + (size_t)(wi0 + l15) * DH + quad * 8;
    f16x8 aq0 = *(const f16x8*)(qrow);
    f16x8 aq1 = *(const f16x8*)(qrow + 32);

    f16* Pw = Pb + w * 16 * 72;

    // ---- build Q'_r A-frags via MFMA (M_r staged transposed in LDS) ----
    f16x8 aqp[RD][2];
#pragma unroll 1
    for (int r = 0; r < RD; ++r) {
        __syncthreads();
        {
            int p = tid >> 2, q0 = (tid & 3) * 16;
            const float* src = bili + ((size_t)(r * NH + n) * DH + p) * DH + q0;
            float4 g0 = ((const float4*)src)[0];
            float4 g1 = ((const float4*)src)[1];
            float4 g2 = ((const float4*)src)[2];
            float4 g3 = ((const float4*)src)[3];
            float mv[16] = {g0.x, g0.y, g0.z, g0.w, g1.x, g1.y, g1.z, g1.w,
                            g2.x, g2.y, g2.z, g2.w, g3.x, g3.y, g3.z, g3.w};
#pragma unroll
            for (int u = 0; u < 16; ++u) Mt[(q0 + u) * 72 + p] = (f16)mv[u];
        }
        __syncthreads();
#pragma unroll
        for (int ns = 0; ns < 4; ++ns) {
            f16x8 b0 = *(const f16x8*)&Mt[(ns * 16 + l15) * 72 + quad * 8];
            f16x8 b1 = *(const f16x8*)&Mt[(ns * 16 + l15) * 72 + quad * 8 + 32];
            f32x4 d = {0.f, 0.f, 0.f, 0.f};
            d = MFMA16(aq0, b0, d);
            d = MFMA16(aq1, b1, d);
#pragma unroll
            for (int reg = 0; reg < 4; ++reg)
                Pw[(quad * 4 + reg) * 72 + ns * 16 + l15] = (f16)d[reg];
        }
        aqp[r][0] = *(const f16x8*)&Pw[l15 * 72 + quad * 8];
        aqp[r][1] = *(const f16x8*)&Pw[l15 * 72 + quad * 8 + 32];
    }

    f16x8 ones;
#pragma unroll
    for (int u = 0; u < 8; ++u) ones[u] = (f16)1.0f;

    f32x4 o[4] = {{0,0,0,0},{0,0,0,0},{0,0,0,0},{0,0,0,0}};
    f32x4 lacc = {0.f, 0.f, 0.f, 0.f};
    float mrun[4] = {-1e30f, -1e30f, -1e30f, -1e30f};

    const unsigned char* adjrow =
        adjp + (size_t)(b * 512 + (wi0 >> 2) + quad) * (S_ * 4);
    const float* maskrow = mask + (size_t)b * S_;
    const f16* vtb = vt + (size_t)bn * DH * S_;

    for (int t = 0; t < 32; ++t) {
        const int j0 = t * 64;
        float sc[4][4];

#pragma unroll
        for (int js = 0; js < 4; ++js) {
            const int jcol = j0 + js * 16 + l15;
            const f16* kp = k + kbase + (size_t)jcol * DH + quad * 8;
            f16x8 bk0 = *(const f16x8*)(kp);
            f16x8 bk1 = *(const f16x8*)(kp + 32);

            f32x4 aqk = {0.f, 0.f, 0.f, 0.f};
            aqk = MFMA16(aq0, bk0, aqk);
            aqk = MFMA16(aq1, bk1, aqk);
            f32x4 ar[RD];
#pragma unroll
            for (int r = 0; r < RD; ++r) {
                f32x4 z = {0.f, 0.f, 0.f, 0.f};
                z = MFMA16(aqp[r][0], bk0, z);
                z = MFMA16(aqp[r][1], bk1, z);
                ar[r] = z;
            }

            uchar4 a4 = *(const uchar4*)(adjrow + (size_t)jcol * 4);
            unsigned int bbits[4] = {a4.x, a4.y, a4.z, a4.w};
            float mkL = maskrow[jcol] * L2E;
#pragma unroll
            for (int reg = 0; reg < 4; ++reg) {
                float s = aqk[reg];
                unsigned int bt = bbits[reg];
#pragma unroll
                for (int r = 0; r < RD; ++r)
                    s = fmaf((float)((bt >> r) & 1u), ar[r][reg], s);
                sc[js][reg] = fmaf(s, SCL, lut[bt] + mkL);
            }
        }

        // ---- online softmax (exp2 domain; rows in 16-lane groups) ----
        float alpha[4];
#pragma unroll
        for (int reg = 0; reg < 4; ++reg) {
            float nm = fmaxf(fmaxf(sc[0][reg], sc[1][reg]),
                             fmaxf(sc[2][reg], sc[3][reg]));
#pragma unroll
            for (int off = 1; off < 16; off <<= 1)
                nm = fmaxf(nm, __shfl_xor(nm, off));
            float mn = fmaxf(mrun[reg], nm);
            alpha[reg] = exp2fast(mrun[reg] - mn);
            mrun[reg] = mn;
        }
#pragma unroll
        for (int js = 0; js < 4; ++js)
#pragma unroll
            for (int reg = 0; reg < 4; ++reg) {
                float p = exp2fast(sc[js][reg] - mrun[reg]);
                Pw[(quad * 4 + reg) * 72 + js * 16 + l15] = (f16)p;
            }
#pragma unroll
        for (int reg = 0; reg < 4; ++reg) {
            lacc[reg] *= alpha[reg];
#pragma unroll
            for (int ds = 0; ds < 4; ++ds) o[ds][reg] *= alpha[reg];
        }

        // ---- PV + row-sum via MFMA ----
        f16x8 pa0 = *(const f16x8*)&Pw[l15 * 72 + quad * 8];
        f16x8 pa1 = *(const f16x8*)&Pw[l15 * 72 + quad * 8 + 32];
        lacc = MFMA16(pa0, ones, lacc);
        lacc = MFMA16(pa1, ones, lacc);
#pragma unroll
        for (int ds = 0; ds < 4; ++ds) {
            const f16* vp = vtb + (size_t)(ds * 16 + l15) * S_ + j0 + quad * 8;
            f16x8 bv0 = *(const f16x8*)(vp);
            f16x8 bv1 = *(const f16x8*)(vp + 32);
            o[ds] = MFMA16(pa0, bv0, o[ds]);
            o[ds] = MFMA16(pa1, bv1, o[ds]);
        }
    }

    // ---- epilogue ----
#pragma unroll
    for (int reg = 0; reg < 4; ++reg) {
        float inv = 1.f / lacc[reg];
        int i = wi0 + quad * 4 + reg;
#pragma unroll
        for (int ds = 0; ds < 4; ++ds)
            out[((size_t)b * S_ + i) * H_ + n * DH + ds * 16 + l15] =
                o[ds][reg] * inv;
    }
}

// ---------------------------------------------------------------------------
extern "C" void kernel_launch(void* const* d_in, const int* in_sizes, int n_in,
                              void* d_out, int out_size, void* d_ws, size_t ws_size,
                              hipStream_t stream)
{
    const float* hs   = (const float*)d_in[0];
    const float* mask = (const float*)d_in[1];
    const float* adj  = (const float*)d_in[2];
    const float* Wq   = (const float*)d_in[3];
    const float* bq   = (const float*)d_in[4];
    const float* Wk   = (const float*)d_in[5];
    const float* bk   = (const float*)d_in[6];
    const float* Wv   = (const float*)d_in[7];
    const float* bv   = (const float*)d_in[8];
    const float* bili = (const float*)d_in[9];
    const float* absb = (const float*)d_in[10];
    float* out = (float*)d_out;

    const size_t QKV = (size_t)BN * S_ * DH;       // 3.1M elems
    f16* q  = (f16*)d_ws;
    f16* k  = q + QKV;
    f16* vt = k + QKV;
    unsigned char* adjp = (unsigned char*)(vt + QKV);       // 8 MB
    f16* xh = (f16*)(adjp + (size_t)B_ * 512 * S_ * 4);
    f16* wh = xh + (size_t)B_ * S_ * H_;                    // Wq|Wk|Wv f16

    const int total4 = NX4 + 3 * NW4;
    cvtall<<<(total4 + 255) / 256, 256, 0, stream>>>(hs, Wq, Wk, Wv, xh, wh);
    qkv_gemm<<<dim3(12, 64), 256, 0, stream>>>(xh, wh, bq, bk, bv, q, k, vt);
    adjpack<<<2048, 256, 0, stream>>>(adj, adjp);
    attn<<<768, 256, 0, stream>>>(q, k, vt, bili, adjp, mask, absb, out);
}